// Round 11
// baseline (78.091 us; speedup 1.0000x reference)
//
#include <hip/hip_runtime.h>
#include <hip/hip_bf16.h>

// Problem constants
#define NBATCH 256
#define NC 273     // C_IN (K)
#define ND 273     // C_OUT (M)
#define NT 360     // T (N)
#define NSUB 128

// GEMM tiling: one block = full D (288 padded) x 64 t-columns (6 tiles cover 360)
// Small acc (36 AGPR) -> <=128 regs/wave -> 2 blocks/CU resident (TLP).
#define THREADS 512
#define BM 288
#define BN 64
#define BK 32
#define LDK 40     // padded LDS row stride (elements) -> 80 B rows, 2-way-free banks
#define KITERS 9   // ceil(273/32)

// wT (bf16, transposed w) in d_ws: [NSUB][288 d][288 c]; c in [273,288) zero
// for d<273 -> GEMM K-tail needs no masking. d in [273,288) garbage, masked at store.
#define WT_LD 288
#define WT_SUBJ (288 * 288)
#define WT_BYTES ((size_t)NSUB * WT_SUBJ * 2)

typedef __bf16 bf16_t;
typedef bf16_t bf16x4 __attribute__((ext_vector_type(4)));
typedef bf16_t bf16x8 __attribute__((ext_vector_type(8)));
typedef float  f32x4  __attribute__((ext_vector_type(4)));

// Raw barrier with NO vmcnt drain: LDS ops fenced manually with lgkmcnt(0);
// outstanding global loads stay in flight across the barrier.
#define LDS_FENCE_BARRIER()                                   \
    do {                                                      \
        asm volatile("s_waitcnt lgkmcnt(0)" ::: "memory");    \
        __builtin_amdgcn_s_barrier();                         \
    } while (0)

// ---- pre-pass: w[s][c][d] fp32 -> wT[s][d][c] bf16 (LDS-tiled transpose) ----
__global__ __launch_bounds__(256) void conv_w(const float* __restrict__ w,
                                              bf16_t* __restrict__ wT) {
    const int bid  = blockIdx.x;       // 128 subjects x 25 tiles
    const int s    = bid / 25;
    const int tile = bid % 25;
    const int c0   = (tile / 5) * 64;
    const int d0   = (tile % 5) * 64;
    const int tx   = threadIdx.x & 63;
    const int ty   = threadIdx.x >> 6; // 0..3

    __shared__ float t[64][65];
    const float* __restrict__ wsrc = w + (size_t)s * NC * ND;
#pragma unroll
    for (int j = 0; j < 16; ++j) {
        const int row = ty + j * 4;           // c-local
        const int c = c0 + row, d = d0 + tx;  // read coalesced along d
        t[row][tx] = (c < NC && d < ND) ? wsrc[c * ND + d] : 0.f;
    }
    __syncthreads();
    bf16_t* __restrict__ wdst = wT + (size_t)s * WT_SUBJ;
#pragma unroll
    for (int j = 0; j < 16; ++j) {
        const int row = ty + j * 4;           // d-local
        const int d = d0 + row, c = c0 + tx;  // write coalesced along c
        if (d < ND && c < WT_LD)
            wdst[d * WT_LD + c] = (bf16_t)t[tx][row];
    }
}

// ---- main GEMM ----
template<bool BF16W>
__global__ __launch_bounds__(THREADS, 4) void subject_gemm(
    const float*  __restrict__ x,        // [B, C, T]
    const int*    __restrict__ subjects, // [B]
    const float*  __restrict__ w,        // [S, C, D] fp32 (fallback path)
    const bf16_t* __restrict__ wT,       // [S, 288, 288] bf16 (main path)
    float*        __restrict__ out)      // [B, D, T]
{
    // 1536 blocks = 8 XCDs x 192 slots; keep a sample's 6 t-tiles on one XCD.
    const int raw  = blockIdx.x;
    const int xcd  = raw & 7;
    const int slot = raw >> 3;          // 0..191
    const int b    = xcd * 32 + slot / 6;
    const int tt   = slot % 6;
    const int t0   = tt * BN;           // 0..320; *4B always 64-B aligned
    const int bnv  = (tt == 5) ? (NT - 5 * BN) : BN;  // 40 or 64 valid cols
    const int s    = subjects[b];

    const float*  __restrict__ xb  = x  + (size_t)b * NC * NT;
    const float*  __restrict__ wsf = w  + (size_t)s * NC * ND;
    const bf16_t* __restrict__ wsb = wT + (size_t)s * WT_SUBJ;

    // Double-buffered LDS: 2 x (288*40 + 64*40) bf16 = 56320 B -> 2 blocks/CU fit
    __shared__ __align__(16) bf16_t As[2][BM * LDK]; // [buf][d][k]
    __shared__ __align__(16) bf16_t Bs[2][BN * LDK]; // [buf][t][k]

    const int tid   = threadIdx.x;
    const int lane  = tid & 63;
    const int wid   = tid >> 6;   // 0..7
    const int wm    = wid >> 2;   // D half: 144 rows
    const int wn    = wid & 3;    // T quarter: 16 cols
    const int l16   = lane & 15;
    const int khalf = lane >> 4;  // 0..3

    // A: 2304 bf16x4-cells; cell i = tid + 512*j: kq = i&7 (fast), d = i>>3
    // -> 8-B loads, 8 lanes cover one contiguous 64-B wT row chunk.
    int offA[5], gA[5], dA[5], cqA[5];
#pragma unroll
    for (int j = 0; j < 5; ++j) {
        const int i  = tid + THREADS * j;
        const int ii = (i < 2304) ? i : 2303;
        const int kq = ii & 7;
        const int d  = ii >> 3;
        offA[j] = d * LDK + kq * 4;
        gA[j]   = d * WT_LD + kq * 4;  // + kk at load time (bf16 elems)
        dA[j]   = d;
        cqA[j]  = kq * 4;
    }
    const bool haveJ4 = (tid < 2304 - 4 * THREADS); // tid < 256, wave-uniform

    // B: 512 cells = (t 0..63 fast) x (kq 0..7); exactly 1 per thread.
    const int tB   = lane;             // t-local = lane -> coalesced
    const int kqB  = wid;              // kq = tid>>6
    const int tcB  = (tB < bnv) ? tB : (bnv - 1);   // clamp pad cols (masked at store)
    const int offB = tB * LDK + kqB * 4;
    const int gBb  = kqB * 4 * NT + t0 + tcB;

    // Single staging set (depth-1; cross-block TLP hides latency).
    bf16x4 aS[5];
    float  bS[4];

    // A load: bf16 path unmasked for ALL tiles incl. K-tail (c<=287<288 in-row;
    // c-pad zeros kill K-tail; d-pad rows garbage masked at store).
    auto loadA = [&](int kk) {
        if constexpr (BF16W) {
#pragma unroll
            for (int j = 0; j < 4; ++j)
                aS[j] = *(const bf16x4*)&wsb[gA[j] + kk];
            if (haveJ4)
                aS[4] = *(const bf16x4*)&wsb[gA[4] + kk];
        } else {
#pragma unroll
            for (int j = 0; j < 5; ++j) {
                if (j == 4 && !haveJ4) break;
                bf16x4 v;
#pragma unroll
                for (int u = 0; u < 4; ++u) {
                    const int c = kk + cqA[j] + u;
                    const float f = (c < NC && dA[j] < ND) ? wsf[c * ND + dA[j]] : 0.f;
                    v[u] = (bf16_t)f;
                }
                aS[j] = v;
            }
        }
    };
    auto loadB = [&](int kk) {
        const int base = kk * NT;
#pragma unroll
        for (int u = 0; u < 4; ++u)
            bS[u] = xb[base + gBb + u * NT];
    };
    // B tail (kk=256): clamp c addr; garbage killed by A's zero c-pad.
    auto loadB_tail = [&]() {
#pragma unroll
        for (int u = 0; u < 4; ++u) {
            const int c  = 256 + kqB * 4 + u;
            const int cc = (c < NC) ? c : (NC - 1);
            bS[u] = xb[cc * NT + t0 + tcB];
        }
    };

    f32x4 acc[9];
#pragma unroll
    for (int m = 0; m < 9; ++m)
        acc[m] = (f32x4){0.f, 0.f, 0.f, 0.f};

    // ---- prologue: tile 0 -> regs -> LDS0 ----
    loadA(0);
    loadB(0);
    {
#pragma unroll
        for (int j = 0; j < 4; ++j) *(bf16x4*)&As[0][offA[j]] = aS[j];
        if (haveJ4)                 *(bf16x4*)&As[0][offA[4]] = aS[4];
        bf16x4 v;
#pragma unroll
        for (int u = 0; u < 4; ++u) v[u] = (bf16_t)bS[u];
        *(bf16x4*)&Bs[0][offB] = v;
    }
    LDS_FENCE_BARRIER();

    // ---- main loop: tile it lives in LDS[it&1]; ONE barrier per iter.
    // Per iter: frag-read cur | issue loads(it+1) | MFMA | stage -> other | barrier.
#define GEMM_ITER(IT, RD, WR)                                                          \
    {                                                                                  \
        bf16x8 af[9];                                                                  \
        const bf16x8 bfr = *(const bf16x8*)&Bs[RD][(wn * 16 + l16) * LDK + khalf * 8]; \
        _Pragma("unroll")                                                              \
        for (int m = 0; m < 9; ++m)                                                    \
            af[m] = *(const bf16x8*)&As[RD][(wm * 144 + m * 16 + l16) * LDK + khalf * 8]; \
        if ((IT) < KITERS - 2)      { loadA(((IT) + 1) * BK); loadB(((IT) + 1) * BK); } \
        else if ((IT) == KITERS - 2){ loadA(256);             loadB_tail(); }          \
        _Pragma("unroll")                                                              \
        for (int m = 0; m < 9; ++m)                                                    \
            acc[m] = __builtin_amdgcn_mfma_f32_16x16x32_bf16(af[m], bfr, acc[m], 0, 0, 0); \
        if ((IT) < KITERS - 1) {                                                       \
            _Pragma("unroll")                                                          \
            for (int j = 0; j < 4; ++j) *(bf16x4*)&As[WR][offA[j]] = aS[j];            \
            if (haveJ4)                 *(bf16x4*)&As[WR][offA[4]] = aS[4];             \
            bf16x4 v;                                                                  \
            _Pragma("unroll")                                                          \
            for (int u = 0; u < 4; ++u) v[u] = (bf16_t)bS[u];                          \
            *(bf16x4*)&Bs[WR][offB] = v;                                               \
            LDS_FENCE_BARRIER();                                                       \
        }                                                                              \
    }

    GEMM_ITER(0, 0, 1)
    GEMM_ITER(1, 1, 0)
    GEMM_ITER(2, 0, 1)
    GEMM_ITER(3, 1, 0)
    GEMM_ITER(4, 0, 1)
    GEMM_ITER(5, 1, 0)
    GEMM_ITER(6, 0, 1)
    GEMM_ITER(7, 1, 0)
    GEMM_ITER(8, 0, 1)
#undef GEMM_ITER

    // Epilogue: C/D layout col(t)=lane&15, row(d)=(lane>>4)*4+reg (verified R1-R10).
    // Store bases (t0 + wn*16)*4 multiple of 64 -> aligned lines.
    float* __restrict__ ob = out + (size_t)b * ND * NT;
    const int tc = wn * 16 + l16;
    const int gt = t0 + tc;
#pragma unroll
    for (int m = 0; m < 9; ++m) {
#pragma unroll
        for (int rg = 0; rg < 4; ++rg) {
            const int d = wm * 144 + m * 16 + khalf * 4 + rg;
            if (d < ND && tc < bnv)
                ob[(size_t)d * NT + gt] = acc[m][rg];
        }
    }
}

extern "C" void kernel_launch(void* const* d_in, const int* in_sizes, int n_in,
                              void* d_out, int out_size, void* d_ws, size_t ws_size,
                              hipStream_t stream) {
    const float* x        = (const float*)d_in[0];
    const int*   subjects = (const int*)d_in[1];
    const float* w        = (const float*)d_in[2];
    float*       out      = (float*)d_out;
    bf16_t*      wT       = (bf16_t*)d_ws;

    const int nblocks = NBATCH * 6; // 1536 = 8 XCDs * 192; 6 t-tiles per sample

    if (ws_size >= WT_BYTES) {
        conv_w<<<NSUB * 25, 256, 0, stream>>>(w, wT);
        subject_gemm<true><<<nblocks, THREADS, 0, stream>>>(x, subjects, w, wT, out);
    } else {
        subject_gemm<false><<<nblocks, THREADS, 0, stream>>>(x, subjects, w, wT, out);
    }
}

// Round 12
// 62.052 us; speedup vs baseline: 1.2585x; 1.2585x over previous
//
#include <hip/hip_runtime.h>
#include <hip/hip_bf16.h>

// Problem constants
#define NBATCH 256
#define NC 273     // C_IN (K)
#define ND 273     // C_OUT (M)
#define NT 360     // T (N)
#define NSUB 128

// GEMM tiling: one block = full D (288 padded) x 120 t-cols (3 tiles cover 360)
#define THREADS 512
#define BM 288
#define BN 128     // B LDS cols (120 valid + 8 clamp-pad)
#define BNV 120
#define BK 32
#define KITERS 9   // ceil(273/32)

// wL: bf16 "cells" [s][cb 0..35][d 0..287] x 8 elems (cell = 8 bf16 = 16 B).
// cell(s,cb,d)[u] = w[s][cb*8+u][d], ZERO if c>=273 or d>=273.
// One GEMM A-tile (kk=it*32 -> cb=it*4..+3) = 1152 cells = 18432 B CONTIGUOUS.
#define NCB 36
#define ACELLS 1152                 // cells per K-tile (4 cb x 288 d)
#define ATILE_BYTES (ACELLS * 16)   // 18432
#define WL_BYTES ((size_t)NSUB * NCB * 288 * 16 + 64)

typedef __bf16 bf16_t;
typedef bf16_t bf16x8 __attribute__((ext_vector_type(8)));
typedef float  f32x4  __attribute__((ext_vector_type(4)));

typedef const __attribute__((address_space(1))) char gconst_char;
typedef __attribute__((address_space(3))) char lds_char;
// 16-B direct global->LDS DMA (dest = wave-uniform base + lane*16)
#define GLOAD16(gsrc, ldst) \
    __builtin_amdgcn_global_load_lds((gconst_char*)(gsrc), (lds_char*)(ldst), 16, 0, 0)

#define SCHED_FENCE() __builtin_amdgcn_sched_barrier(0)

// ---- pre-pass: w[s][c][d] fp32 -> wL cells (coalesced both sides, no LDS) ----
__global__ __launch_bounds__(256) void conv_w(const float* __restrict__ w,
                                              bf16_t* __restrict__ wL) {
    const int bid = blockIdx.x;           // s*36 + cb
    const int s   = bid / NCB;
    const int cb  = bid % NCB;
    const float* __restrict__ wsrc = w + (size_t)s * NC * ND;
    bf16_t* __restrict__ dst = wL + ((size_t)(s * NCB + cb) * 288) * 8;

#pragma unroll
    for (int j = 0; j < 2; ++j) {
        const int d = threadIdx.x + j * 256;
        if (d >= 288) break;              // j==1 active only for tid<32
        bf16x8 v;
#pragma unroll
        for (int u = 0; u < 8; ++u) {
            const int c = cb * 8 + u;
            const float f = (c < NC && d < ND) ? wsrc[c * ND + d] : 0.f; // reads coalesced along d
            v[u] = (bf16_t)f;
        }
        *(bf16x8*)&dst[(size_t)d * 8] = v; // writes contiguous along d
    }
}

// ---- main GEMM ----
template<bool FAST>
__global__ __launch_bounds__(THREADS, 2) void subject_gemm(
    const float*  __restrict__ x,        // [B, C, T]
    const int*    __restrict__ subjects, // [B]
    const float*  __restrict__ w,        // [S, C, D] fp32 (fallback path)
    const bf16_t* __restrict__ wL,       // cells (main path)
    float*        __restrict__ out)      // [B, D, T]
{
    // 768 blocks = 8 XCDs x 96 slots; a sample's 3 t-tiles share an XCD.
    const int raw  = blockIdx.x;
    const int xcd  = raw & 7;
    const int slot = raw >> 3;          // 0..95
    const int b    = xcd * 32 + slot / 3;
    const int tt   = slot % 3;
    const int t0   = tt * BNV;
    const int s    = subjects[b];

    const float*  __restrict__ xb  = x + (size_t)b * NC * NT;
    const float*  __restrict__ wsf = w + (size_t)s * NC * ND;
    const char*   __restrict__ wlb = (const char*)(wL + (size_t)s * NCB * 288 * 8);

    // A: DMA-filled, linear cell layout [cbl 0..3][d 0..287] (16 B cells).
    // B: cell layout [kq8 0..3][t 0..127] (16 B cells) -> conflict-free writes/reads.
    __shared__ __align__(16) bf16_t Asm[2][ACELLS * 8];  // 18432 B each
    __shared__ __align__(16) bf16_t Bsm[2][512 * 8];     // 8192 B each

    const int tid   = threadIdx.x;
    const int lane  = tid & 63;
    const int wid   = tid >> 6;   // 0..7
    const int wm    = wid >> 2;   // D half: 144 rows
    const int wn    = wid & 3;    // T quarter: 32 cols
    const int l16   = lane & 15;
    const int khalf = lane >> 4;  // 0..3

    // B staging: one cell/thread: (kq8 = tid>>7, t = tid&127)
    const int tB   = tid & 127;
    const int kq8  = tid >> 7;
    const int tcB  = (tB < BNV) ? tB : (BNV - 1);  // clamp pad cols (masked at store)
    const int xcol = t0 + tcB;

    float bEv[8], bOd[8];   // NAMED depth-2 B staging (never runtime-indexed)

    auto loadBreg = [&](float (&r)[8], int kk) {
#pragma unroll
        for (int u = 0; u < 8; ++u)
            r[u] = xb[(kk + kq8 * 8 + u) * NT + xcol];   // lanes t-fast: coalesced
    };
    auto loadBregTail = [&](float (&r)[8]) {             // kk = 256
#pragma unroll
        for (int u = 0; u < 8; ++u) {
            const int c  = 256 + kq8 * 8 + u;
            const int cc = (c < NC) ? c : (NC - 1);      // clamp addr; A zeros kill garbage
            r[u] = xb[cc * NT + xcol];
        }
    };
    auto writeB = [&](const float (&r)[8], bf16_t* Bbuf) {
        bf16x8 v;
#pragma unroll
        for (int u = 0; u < 8; ++u) v[u] = (bf16_t)r[u];
        *(bf16x8*)&Bbuf[(kq8 * BN + tB) * 8] = v;        // contiguous 16 B, clean banks
    };
    // A staging: FAST = 2-3 global_load_lds_dwordx4 per thread, fully contiguous.
    auto stageA = [&](int it, bf16_t* Abuf) {
        if constexpr (FAST) {
            const char* src = wlb + (size_t)it * ATILE_BYTES;
            char* dst = (char*)Abuf;
            GLOAD16(src + (size_t)tid * 16,          dst + tid * 16);
            GLOAD16(src + (size_t)(tid + 512) * 16,  dst + (tid + 512) * 16);
            if (tid < 128)   // wave-uniform (waves 0,1)
                GLOAD16(src + (size_t)(tid + 1024) * 16, dst + (tid + 1024) * 16);
        } else {
            // emergency fp32 path: reg-load + cvt + ds_write (slow, correct)
            const int kk = it * BK;
#pragma unroll
            for (int j = 0; j < 3; ++j) {
                const int i = tid + 512 * j;
                if (i >= ACELLS) break;              // wave-uniform
                const int cbl = i / 288, d = i % 288;
                bf16x8 v;
#pragma unroll
                for (int u = 0; u < 8; ++u) {
                    const int c = kk + cbl * 8 + u;
                    const float f = (c < NC && d < ND) ? wsf[c * ND + d] : 0.f;
                    v[u] = (bf16_t)f;
                }
                *(bf16x8*)((char*)Abuf + (size_t)i * 16) = v;
            }
        }
    };

    f32x4 acc[9][2];
#pragma unroll
    for (int m = 0; m < 9; ++m)
#pragma unroll
        for (int n = 0; n < 2; ++n)
            acc[m][n] = (f32x4){0.f, 0.f, 0.f, 0.f};

    // ---- prologue ----
    loadBreg(bEv, 0);            // B(0)
    SCHED_FENCE();
    stageA(0, &Asm[0][0]);       // A(0) DMA -> buf0
    SCHED_FENCE();
    loadBreg(bOd, BK);           // B(1) in flight
    SCHED_FENCE();
    writeB(bEv, &Bsm[0][0]);     // auto counted-vmcnt waits B(0); A(0)+B(1) stay in flight
    asm volatile("s_waitcnt vmcnt(8)" ::: "memory");   // A(0) done; B(1)=8 newest remain
    asm volatile("s_waitcnt lgkmcnt(0)" ::: "memory");
    SCHED_FENCE();
    __builtin_amdgcn_s_barrier();

    // ---- main loop: tile it lives in buf it&1 ----
    // Per iter: frag reads | stage A(it+1) DMA | write B(it+1) | load B(it+2) regs
    //           | lgkm0 | MFMA | counted vmcnt (A drained, B it+2 in flight) | barrier
#define G_ITER(IT, RD, WR, BCUR, BNXT)                                                     \
    {                                                                                      \
        bf16x8 af[9], bfr[2];                                                              \
        _Pragma("unroll")                                                                  \
        for (int n = 0; n < 2; ++n)                                                        \
            bfr[n] = *(const bf16x8*)&Bsm[RD][(khalf * BN + wn * 32 + n * 16 + l16) * 8];  \
        _Pragma("unroll")                                                                  \
        for (int m = 0; m < 9; ++m)                                                        \
            af[m] = *(const bf16x8*)&Asm[RD][(khalf * 288 + wm * 144 + m * 16 + l16) * 8]; \
        if ((IT) < KITERS - 1) {                                                           \
            stageA((IT) + 1, &Asm[WR][0]);                                                 \
            SCHED_FENCE();                                                                 \
            writeB(BNXT, &Bsm[WR][0]);                                                     \
        }                                                                                  \
        if ((IT) < KITERS - 2)      loadBreg(BCUR, ((IT) + 2) * BK);                       \
        else if ((IT) == KITERS - 2) loadBregTail(BCUR);                                   \
        SCHED_FENCE();                                                                     \
        asm volatile("s_waitcnt lgkmcnt(0)" ::: "memory");                                 \
        SCHED_FENCE();                                                                     \
        _Pragma("unroll")                                                                  \
        for (int m = 0; m < 9; ++m)                                                        \
            _Pragma("unroll")                                                              \
            for (int n = 0; n < 2; ++n)                                                    \
                acc[m][n] = __builtin_amdgcn_mfma_f32_16x16x32_bf16(af[m], bfr[n],         \
                                                                    acc[m][n], 0, 0, 0);   \
        if ((IT) < KITERS - 1) {                                                           \
            if ((IT) < KITERS - 2)                                                         \
                asm volatile("s_waitcnt vmcnt(8)" ::: "memory"); /* A done, B(it+2) fly */ \
            else                                                                           \
                asm volatile("s_waitcnt vmcnt(0)" ::: "memory"); /* last stage: drain  */  \
            SCHED_FENCE();                                                                 \
            __builtin_amdgcn_s_barrier();                                                  \
        }                                                                                  \
    }

    G_ITER(0, 0, 1, bEv, bOd)
    G_ITER(1, 1, 0, bOd, bEv)
    G_ITER(2, 0, 1, bEv, bOd)
    G_ITER(3, 1, 0, bOd, bEv)
    G_ITER(4, 0, 1, bEv, bOd)
    G_ITER(5, 1, 0, bOd, bEv)
    G_ITER(6, 0, 1, bEv, bOd)
    G_ITER(7, 1, 0, bOd, bEv)   // stages tile 8 (even -> bEv) into buf0; vmcnt(0)
    G_ITER(8, 0, 1, bEv, bOd)   // final: compute only
#undef G_ITER

    // Epilogue: C/D layout col(t)=lane&15, row(d)=(lane>>4)*4+reg (verified R1-R11)
    float* __restrict__ ob = out + (size_t)b * ND * NT;
#pragma unroll
    for (int m = 0; m < 9; ++m) {
#pragma unroll
        for (int n = 0; n < 2; ++n) {
            const int tc = wn * 32 + n * 16 + l16;
            const int gt = t0 + tc;
#pragma unroll
            for (int rg = 0; rg < 4; ++rg) {
                const int d = wm * 144 + m * 16 + khalf * 4 + rg;
                if (d < ND && tc < BNV)
                    ob[(size_t)d * NT + gt] = acc[m][n][rg];
            }
        }
    }
}

extern "C" void kernel_launch(void* const* d_in, const int* in_sizes, int n_in,
                              void* d_out, int out_size, void* d_ws, size_t ws_size,
                              hipStream_t stream) {
    const float* x        = (const float*)d_in[0];
    const int*   subjects = (const int*)d_in[1];
    const float* w        = (const float*)d_in[2];
    float*       out      = (float*)d_out;
    bf16_t*      wL       = (bf16_t*)d_ws;

    const int nblocks = NBATCH * 3; // 768 = 8 XCDs * 96

    if (ws_size >= WL_BYTES) {
        conv_w<<<NSUB * NCB, 256, 0, stream>>>(w, wL);
        subject_gemm<true><<<nblocks, THREADS, 0, stream>>>(x, subjects, w, wL, out);
    } else {
        subject_gemm<false><<<nblocks, THREADS, 0, stream>>>(x, subjects, w, wL, out);
    }
}